// Round 24
// baseline (5616.612 us; speedup 1.0000x reference)
//
#include <hip/hip_runtime.h>
#include <hip/hip_bf16.h>

// ---------------------------------------------------------------------------
// ContrastiveMambaEncoder. Round 24: scan v7 — p-split 2-way (each block owns
// 32 of 64 p-rows; disjoint y writes, no fixup) + 8-step chunks (LDS 44->24KiB)
// -> grid 512->1024 = 4 blocks/CU (was 2). Identical arithmetic order per
// (p,n) -> bitwise-same output. Everything else = round 23.
// ---------------------------------------------------------------------------

typedef __attribute__((ext_vector_type(4))) float f32x4;
typedef __attribute__((ext_vector_type(4))) short s16x4;
typedef __attribute__((ext_vector_type(8))) short s16x8;

#define DEV __device__ __forceinline__

DEV short f2bf(float f) {
  union { float f; unsigned u; } x; x.f = f;
  unsigned r = x.u + 0x7fffu + ((x.u >> 16) & 1u);
  return (short)(r >> 16);
}
DEV float bf2f(short h) {
  union { unsigned u; float f; } x; x.u = ((unsigned)(unsigned short)h) << 16;
  return x.f;
}
DEV float gelu_f(float x) {
  float u = 0.7978845608028654f * (x + 0.044715f * x * x * x);
  return 0.5f * x * (1.f + tanhf(u));
}
DEV float silu_f(float x) { return x / (1.f + __expf(-x)); }

DEV void glds16(const short* g, short* l) {
  __builtin_amdgcn_global_load_lds(
      (const __attribute__((address_space(1))) void*)g,
      (__attribute__((address_space(3))) void*)l, 16, 0, 0);
}
DEV void glds16f(const float* g, float* l) {
  __builtin_amdgcn_global_load_lds(
      (const __attribute__((address_space(1))) void*)g,
      (__attribute__((address_space(3))) void*)l, 16, 0, 0);
}
DEV void glds4f(const float* g, float* l) {
  __builtin_amdgcn_global_load_lds(
      (const __attribute__((address_space(1))) void*)g,
      (__attribute__((address_space(3))) void*)l, 4, 0, 0);
}

DEV float block_reduce_sum_256(float v, float* red) {
  #pragma unroll
  for (int o = 1; o < 64; o <<= 1) v += __shfl_xor(v, o);
  __syncthreads();
  if ((threadIdx.x & 63) == 0) red[threadIdx.x >> 6] = v;
  __syncthreads();
  return red[0] + red[1] + red[2] + red[3];
}

DEV float wave_reduce_sum(float v) {
  #pragma unroll
  for (int o = 1; o < 64; o <<= 1) v += __shfl_xor(v, o);
  return v;
}

// ---------------------------------------------------------------------------
// Weight prep (batched over all 12 layers).
// ---------------------------------------------------------------------------
__global__ __launch_bounds__(256) void transconv4_all_kernel(
    const float* __restrict__ Wq, const float* __restrict__ Wk,
    const float* __restrict__ Wv, const float* __restrict__ Wo,
    short* __restrict__ Wall)
{
  int l = blockIdx.z >> 2, which = blockIdx.z & 3;
  const float* Wb = (which == 0) ? Wq : (which == 1) ? Wk : (which == 2) ? Wv : Wo;
  const float* W = Wb + (size_t)l * 589824;
  short* Wtz = Wall + (size_t)l * 7077888 + (size_t)which * 589824;
  __shared__ float tile[32][33];
  int tx = threadIdx.x & 31, ty = threadIdx.x >> 5;
  int n0 = blockIdx.x * 32, k0 = blockIdx.y * 32;
  #pragma unroll
  for (int i = 0; i < 4; i++)
    tile[ty + i * 8][tx] = W[(size_t)(k0 + ty + i * 8) * 768 + n0 + tx];
  __syncthreads();
  #pragma unroll
  for (int i = 0; i < 4; i++)
    Wtz[(size_t)(n0 + ty + i * 8) * 768 + k0 + tx] = f2bf(tile[tx][ty + i * 8]);
}

__global__ __launch_bounds__(256) void transconv_f1_all_kernel(
    const float* __restrict__ Wf1, short* __restrict__ Wall)
{
  int l = blockIdx.z;
  const float* W = Wf1 + (size_t)l * 2359296;
  short* Wt = Wall + (size_t)l * 7077888 + 2359296;
  __shared__ float tile[32][33];
  int tx = threadIdx.x & 31, ty = threadIdx.x >> 5;
  int n0 = blockIdx.x * 32, k0 = blockIdx.y * 32;
  #pragma unroll
  for (int i = 0; i < 4; i++)
    tile[ty + i * 8][tx] = W[(size_t)(k0 + ty + i * 8) * 3072 + n0 + tx];
  __syncthreads();
  #pragma unroll
  for (int i = 0; i < 4; i++)
    Wt[(size_t)(n0 + ty + i * 8) * 768 + k0 + tx] = f2bf(tile[tx][ty + i * 8]);
}

__global__ __launch_bounds__(256) void transconv_f2_all_kernel(
    const float* __restrict__ Wf2, short* __restrict__ Wall)
{
  int l = blockIdx.z;
  const float* W = Wf2 + (size_t)l * 2359296;
  short* Wt = Wall + (size_t)l * 7077888 + 4718592;
  __shared__ float tile[32][33];
  int tx = threadIdx.x & 31, ty = threadIdx.x >> 5;
  int n0 = blockIdx.x * 32, k0 = blockIdx.y * 32;
  #pragma unroll
  for (int i = 0; i < 4; i++)
    tile[ty + i * 8][tx] = W[(size_t)(k0 + ty + i * 8) * 768 + n0 + tx];
  __syncthreads();
  #pragma unroll
  for (int i = 0; i < 4; i++)
    Wt[(size_t)(n0 + ty + i * 8) * 3072 + k0 + tx] = f2bf(tile[tx][ty + i * 8]);
}

__global__ __launch_bounds__(256) void transconv_kernel(
    const float* __restrict__ W, short* __restrict__ Wt,
    int K, int N, int Npad)
{
  __shared__ float tile[32][33];
  int tx = threadIdx.x & 31, ty = threadIdx.x >> 5;
  int n0 = blockIdx.x * 32, k0 = blockIdx.y * 32;
  #pragma unroll
  for (int i = 0; i < 4; i++) {
    int k = k0 + ty + i * 8, n = n0 + tx;
    tile[ty + i * 8][tx] = (k < K && n < N) ? W[(size_t)k * N + n] : 0.f;
  }
  __syncthreads();
  #pragma unroll
  for (int i = 0; i < 4; i++) {
    int n = n0 + ty + i * 8, k = k0 + tx;
    if (n < Npad && k < K)
      Wt[(size_t)n * K + k] = f2bf(tile[tx][ty + i * 8]);
  }
}

__global__ void concatbias_all_kernel(const float* __restrict__ bq,
                                      const float* __restrict__ bk,
                                      const float* __restrict__ bv,
                                      float* __restrict__ cb)
{
  int i = blockIdx.x * 256 + threadIdx.x;
  if (i >= 12 * 2304) return;
  int l = i / 2304, c = i - l * 2304;
  cb[i] = (c < 768) ? bq[l * 768 + c]
        : (c < 1536) ? bk[l * 768 + c - 768] : bv[l * 768 + c - 1536];
}

// ---------------------------------------------------------------------------
// gemm3: round-9 counted-vmcnt schedule; BM template param; col<N guard.
// ---------------------------------------------------------------------------
template<int OUTMODE, int WN, int BM>
__global__ __launch_bounds__(512) void gemm3(
    const short* __restrict__ A, const short* __restrict__ Bt,
    const float* __restrict__ bias, short* __restrict__ Cout,
    int M, int N, int K)
{
  constexpr int BN = 64 * WN;
  constexpr int MI = (BM * WN) / 128;
  constexpr int WROWS = 16 * MI;
  constexpr int VMC = BM / 64 + BN / 64;
  __shared__ short As[2][BM * 64];
  __shared__ short Bs[2][BN * 64];
  const int t = threadIdx.x;
  const int lane = t & 63;
  const int lr = lane & 15, lg = lane >> 4;
  const int wid = t >> 6;
  const int wr = (WN == 4) ? (wid >> 2) : (wid >> 1);
  const int wc = (WN == 4) ? (wid & 3) : (wid & 1);

  const int nwg = gridDim.x * gridDim.y;
  const int lid = blockIdx.y * gridDim.x + blockIdx.x;
  const int xcd = lid & 7, rest = lid >> 3;
  const int qq = nwg >> 3, rr = nwg & 7;
  const int wgid = (xcd < rr ? xcd * (qq + 1) : rr * (qq + 1) + (xcd - rr) * qq) + rest;
  const int m0 = (wgid / gridDim.x) * BM;
  const int n0 = (wgid % gridDim.x) * BN;

  const short* Ab = A + (size_t)m0 * K;
  const short* Bb = Bt + (size_t)n0 * K;

  auto stage = [&](int buf, int k0) {
    #pragma unroll
    for (int i = 0; i < BM / 64; i++) {
      int idx = t + 512 * i;
      int row = idx >> 3, c = idx & 7;
      int cs = c ^ (row & 7);
      glds16(Ab + (size_t)row * K + k0 + cs * 8, &As[buf][idx * 8]);
    }
    #pragma unroll
    for (int i = 0; i < BN / 64; i++) {
      int idx = t + 512 * i;
      int row = idx >> 3, c = idx & 7;
      int cs = c ^ (row & 7);
      glds16(Bb + (size_t)row * K + k0 + cs * 8, &Bs[buf][idx * 8]);
    }
  };

  f32x4 acc[MI][4] = {};
  const int nt = K >> 6;

  stage(0, 0);
  stage(1, 64);

  for (int tt = 0; tt < nt; ++tt) {
    const int cur = tt & 1;
    if (tt + 1 < nt) {
      if constexpr (VMC == 8)      asm volatile("s_waitcnt vmcnt(8)" ::: "memory");
      else if constexpr (VMC == 6) asm volatile("s_waitcnt vmcnt(6)" ::: "memory");
      else                         asm volatile("s_waitcnt vmcnt(4)" ::: "memory");
    } else {
      asm volatile("s_waitcnt vmcnt(0)" ::: "memory");
    }
    __builtin_amdgcn_s_barrier();
    asm volatile("" ::: "memory");
    __builtin_amdgcn_sched_barrier(0);

    s16x8 af[MI][2], bfr[4][2];
    #pragma unroll
    for (int mi = 0; mi < MI; mi++) {
      int row = wr * WROWS + mi * 16 + lr;
      #pragma unroll
      for (int ks = 0; ks < 2; ks++) {
        int ck = (ks * 4 + lg) ^ (lr & 7);
        af[mi][ks] = *(const s16x8*)&As[cur][row * 64 + ck * 8];
      }
    }
    #pragma unroll
    for (int ni = 0; ni < 4; ni++) {
      int row = wc * 64 + ni * 16 + lr;
      #pragma unroll
      for (int ks = 0; ks < 2; ks++) {
        int ck = (ks * 4 + lg) ^ (lr & 7);
        bfr[ni][ks] = *(const s16x8*)&Bs[cur][row * 64 + ck * 8];
      }
    }
    asm volatile("s_waitcnt lgkmcnt(0)" ::: "memory");
    __builtin_amdgcn_sched_barrier(0);
    __builtin_amdgcn_s_barrier();
    asm volatile("" ::: "memory");
    __builtin_amdgcn_sched_barrier(0);

    if (tt + 2 < nt) stage(cur, (tt + 2) * 64);

    __builtin_amdgcn_s_setprio(1);
    #pragma unroll
    for (int ks = 0; ks < 2; ks++)
      #pragma unroll
      for (int mi = 0; mi < MI; mi++)
        #pragma unroll
        for (int ni = 0; ni < 4; ni++)
          acc[mi][ni] = __builtin_amdgcn_mfma_f32_16x16x32_bf16(
              af[mi][ks], bfr[ni][ks], acc[mi][ni], 0, 0, 0);
    __builtin_amdgcn_s_setprio(0);
  }

  #pragma unroll
  for (int mi = 0; mi < MI; mi++) {
    int row = m0 + wr * WROWS + mi * 16 + lg * 4;
    #pragma unroll
    for (int ni = 0; ni < 4; ni++) {
      int col = n0 + wc * 64 + ni * 16 + lr;
      if (col >= N) continue;     // uniform guard (padded-Bt call sites)
      float bv = bias ? bias[col] : 0.f;
      #pragma unroll
      for (int r = 0; r < 4; r++) {
        float v = acc[mi][ni][r] + bv;
        if (OUTMODE == 2) v = gelu_f(v);
        Cout[(size_t)(row + r) * N + col] = f2bf(v);
      }
    }
  }
}

// ---------------------------------------------------------------------------
// GEMM (m97 structure) — W_out head gemm (f32 out).
// ---------------------------------------------------------------------------
template<int OUTMODE>
__global__ __launch_bounds__(256) void gemm2(
    const short* __restrict__ A, const short* __restrict__ Bt,
    const float* __restrict__ bias, void* __restrict__ Cout,
    int M, int N, int K)
{
  __shared__ short As[128 * 64];
  __shared__ short Bs[128 * 64];
  const int t = threadIdx.x;
  const int lane = t & 63;
  const int lr = lane & 15, lg = lane >> 4;
  const int wid = t >> 6, wm = wid >> 1, wn = wid & 1;

  const int nwg = gridDim.x * gridDim.y;
  const int lid = blockIdx.y * gridDim.x + blockIdx.x;
  const int xcd = lid & 7, rest = lid >> 3;
  const int qq = nwg >> 3, rr = nwg & 7;
  const int wgid = (xcd < rr ? xcd * (qq + 1) : rr * (qq + 1) + (xcd - rr) * qq) + rest;
  const int m0 = (wgid / gridDim.x) * 128;
  const int n0 = (wgid % gridDim.x) * 128;

  f32x4 acc[4][4] = {};
  const short* Ab = A + (size_t)m0 * K;
  const short* Bb = Bt + (size_t)n0 * K;

  for (int k0 = 0; k0 < K; k0 += 64) {
    __syncthreads();
    #pragma unroll
    for (int i = 0; i < 4; i++) {
      int idx = t + 256 * i;
      int row = idx >> 3, c = idx & 7;
      glds16(Ab + (size_t)row * K + k0 + c * 8, &As[idx * 8]);
    }
    #pragma unroll
    for (int i = 0; i < 4; i++) {
      int idx = t + 256 * i;
      int row = idx >> 3, c = idx & 7;
      glds16(Bb + (size_t)row * K + k0 + c * 8, &Bs[idx * 8]);
    }
    __syncthreads();
    #pragma unroll
    for (int ks = 0; ks < 2; ks++) {
      s16x8 af[4], bfr[4];
      #pragma unroll
      for (int mi = 0; mi < 4; mi++)
        af[mi] = *(const s16x8*)&As[(wm * 64 + mi * 16 + lr) * 64 + ks * 32 + lg * 8];
      #pragma unroll
      for (int ni = 0; ni < 4; ni++)
        bfr[ni] = *(const s16x8*)&Bs[(wn * 64 + ni * 16 + lr) * 64 + ks * 32 + lg * 8];
      #pragma unroll
      for (int mi = 0; mi < 4; mi++)
        #pragma unroll
        for (int ni = 0; ni < 4; ni++)
          acc[mi][ni] = __builtin_amdgcn_mfma_f32_16x16x32_bf16(
              af[mi], bfr[ni], acc[mi][ni], 0, 0, 0);
    }
  }

  #pragma unroll
  for (int mi = 0; mi < 4; mi++) {
    int row = m0 + wm * 64 + mi * 16 + lg * 4;
    #pragma unroll
    for (int ni = 0; ni < 4; ni++) {
      int col = n0 + wn * 64 + ni * 16 + lr;
      if (col >= N) continue;
      float bv = bias ? bias[col] : 0.f;
      #pragma unroll
      for (int r = 0; r < 4; r++) {
        float v = acc[mi][ni][r] + bv;
        if (OUTMODE == 2) v = gelu_f(v);
        size_t off = (size_t)(row + r) * N + col;
        if (OUTMODE == 0) ((float*)Cout)[off] = v;
        else              ((short*)Cout)[off] = f2bf(v);
      }
    }
  }
}

// ---------------------------------------------------------------------------
// Flash attention (QBLK=128, constant-shift softmax).
// ---------------------------------------------------------------------------
#define LDQ 2304
__global__ __launch_bounds__(512) void attn_kernel(
    const short* __restrict__ QKV, const float* __restrict__ biasv,
    short* __restrict__ O)
{
  __shared__ short Ks[64 * 72];
  __shared__ short Vt[64 * 68];
  __shared__ float bsh[64];
  const int t = threadIdx.x;
  const int lane = t & 63, wid = t >> 6;
  const int lr = lane & 15, lg = lane >> 4;
  const int b = blockIdx.z, h = blockIdx.y, q0 = blockIdx.x * 128;
  const float scale = 0.125f;

  s16x8 qf8[2];
  {
    const short* qp = QKV + (size_t)(b * 512 + q0 + wid * 16 + lr) * LDQ + h * 64;
    qf8[0] = *(const s16x8*)(qp + lg * 8);
    qf8[1] = *(const s16x8*)(qp + 32 + lg * 8);
  }

  f32x4 ot[4] = {};
  float lrun = 0.f;

  for (int kv0 = 0; kv0 < 512; kv0 += 64) {
    __syncthreads();
    {
      int row = t >> 3, c8 = (t & 7) * 8;
      *(s16x8*)&Ks[row * 72 + c8] =
          *(const s16x8*)(QKV + (size_t)(b * 512 + kv0 + row) * LDQ + 768 + h * 64 + c8);
    }
    {
      int kk = t & 63, dh = t >> 6;
      const short* vp = QKV + (size_t)(b * 512 + kv0 + kk) * LDQ + 1536 + h * 64 + dh * 8;
      s16x8 v0 = *(const s16x8*)vp;
      #pragma unroll
      for (int i = 0; i < 8; i++) Vt[(dh * 8 + i) * 68 + kk] = v0[i];
    }
    if (t < 64) bsh[t] = biasv[b * 512 + kv0 + t];
    __syncthreads();

    f32x4 st[4] = {};
    #pragma unroll
    for (int ks = 0; ks < 2; ks++) {
      #pragma unroll
      for (int a = 0; a < 4; a++) {
        s16x8 kf = *(const s16x8*)&Ks[(a * 16 + lr) * 72 + ks * 32 + lg * 8];
        st[a] = __builtin_amdgcn_mfma_f32_16x16x32_bf16(kf, qf8[ks], st[a], 0, 0, 0);
      }
    }
    float p[16];
    float rsum = 0.f;
    #pragma unroll
    for (int a = 0; a < 4; a++)
      #pragma unroll
      for (int r = 0; r < 4; r++) {
        float v = __expf(st[a][r] * scale + bsh[a * 16 + lg * 4 + r]);
        p[a * 4 + r] = v;
        rsum += v;
      }
    rsum += __shfl_xor(rsum, 16);
    rsum += __shfl_xor(rsum, 32);
    lrun += rsum;
    s16x4 ptf[4];
    #pragma unroll
    for (int ks = 0; ks < 4; ks++) {
      s16x4 f;
      #pragma unroll
      for (int j = 0; j < 4; j++) f[j] = f2bf(p[ks * 4 + j]);
      ptf[ks] = f;
    }
    #pragma unroll
    for (int ks = 0; ks < 4; ks++) {
      #pragma unroll
      for (int d = 0; d < 4; d++) {
        s16x4 vf = *(const s16x4*)&Vt[(d * 16 + lr) * 68 + ks * 16 + lg * 4];
        ot[d] = __builtin_amdgcn_mfma_f32_16x16x16bf16_1k(vf, ptf[ks], ot[d], 0, 0, 0);
      }
    }
  }

  float inv = 1.f / lrun;
  short* op = O + (size_t)(b * 512 + q0 + wid * 16 + lr) * 768 + h * 64;
  #pragma unroll
  for (int d = 0; d < 4; d++) {
    s16x4 w;
    #pragma unroll
    for (int r = 0; r < 4; r++) w[r] = f2bf(ot[d][r] * inv);
    *(s16x4*)(op + d * 16 + lg * 4) = w;
  }
}

// ---------------------------------------------------------------------------
// Elementwise / norm / head kernels
// ---------------------------------------------------------------------------
__global__ void maskbias_kernel(const int* __restrict__ mask, float* __restrict__ biasv) {
  int i = blockIdx.x * 256 + threadIdx.x;
  if (i < 32 * 512) biasv[i] = mask[i] > 0 ? -8.0f : -1e9f;
}

__global__ __launch_bounds__(256) void embed_ln_kernel(
    const int* __restrict__ ids, const float* __restrict__ tok,
    const float* __restrict__ pos, const float* __restrict__ typ,
    const float* __restrict__ g, const float* __restrict__ bta,
    short* __restrict__ xb)
{
  __shared__ float red[4];
  int row = blockIdx.x, s = row & 511, t = threadIdx.x;
  int id = ids[row];
  float v[3], sum = 0.f;
  #pragma unroll
  for (int i = 0; i < 3; i++) {
    int c = t + 256 * i;
    float e = tok[(size_t)id * 768 + c] + pos[s * 768 + c] + typ[c];
    v[i] = e; sum += e;
  }
  float mean = block_reduce_sum_256(sum, red) * (1.f / 768.f);
  float var = 0.f;
  #pragma unroll
  for (int i = 0; i < 3; i++) { float d = v[i] - mean; var += d * d; }
  var = block_reduce_sum_256(var, red) * (1.f / 768.f);
  float rstd = rsqrtf(var + 1e-12f);
  #pragma unroll
  for (int i = 0; i < 3; i++) {
    int c = t + 256 * i;
    float o = (v[i] - mean) * rstd * g[c] + bta[c];
    xb[(size_t)row * 768 + c] = f2bf(o);
  }
}

__global__ __launch_bounds__(256) void add_ln_kernel(
    short* __restrict__ xb, const short* __restrict__ delta,
    const float* __restrict__ g, const float* __restrict__ bta)
{
  const int t = threadIdx.x;
  const int lane = t & 63, w = t >> 6;
  const int row = blockIdx.x * 4 + w;
  short* xp = xb + (size_t)row * 768;
  const short* dp = delta + (size_t)row * 768;

  float e[12];
  float sum = 0.f;
  #pragma unroll
  for (int i = 0; i < 3; i++) {
    int c4 = (lane + 64 * i) * 4;
    s16x4 xv = *(const s16x4*)(xp + c4);
    s16x4 dv = *(const s16x4*)(dp + c4);
    #pragma unroll
    for (int j = 0; j < 4; j++) {
      float v = bf2f(xv[j]) + bf2f(dv[j]);
      e[i * 4 + j] = v; sum += v;
    }
  }
  float mean = wave_reduce_sum(sum) * (1.f / 768.f);
  float var = 0.f;
  #pragma unroll
  for (int i = 0; i < 12; i++) { float d = e[i] - mean; var += d * d; }
  var = wave_reduce_sum(var) * (1.f / 768.f);
  float rstd = rsqrtf(var + 1e-12f);
  #pragma unroll
  for (int i = 0; i < 3; i++) {
    int c4 = (lane + 64 * i) * 4;
    f32x4 gv = *(const f32x4*)(g + c4);
    f32x4 bv = *(const f32x4*)(bta + c4);
    s16x4 o;
    #pragma unroll
    for (int j = 0; j < 4; j++)
      o[j] = f2bf((e[i * 4 + j] - mean) * rstd * gv[j] + bv[j]);
    *(s16x4*)(xp + c4) = o;
  }
}

__global__ void dtda_kernel(const short* __restrict__ zx,
                            const float* __restrict__ dt_bias,
                            const float* __restrict__ A_log,
                            float* __restrict__ dt, float* __restrict__ dA)
{
  int i = blockIdx.x * 256 + threadIdx.x;
  if (i >= 16384 * 16) return;
  int row = i >> 4, h = i & 15;
  float x = bf2f(zx[(size_t)row * 2320 + 2304 + h]) + dt_bias[h];
  float sp = (x > 20.f) ? x : log1pf(__expf(x));
  float a = -__expf(A_log[h]);
  dt[i] = sp;
  dA[i] = __expf(sp * a);
}

__global__ __launch_bounds__(256) void conv2_kernel(
    const short* __restrict__ zx, const float* __restrict__ cw,
    const float* __restrict__ cb, float* __restrict__ xc)
{
  int gid = blockIdx.x * 256 + threadIdx.x;
  int row = gid / 160, cg = gid - row * 160;
  if (row >= 16384) return;
  int s = row & 511, c0 = cg * 8;
  float acc[8];
  #pragma unroll
  for (int j = 0; j < 8; j++) acc[j] = cb[c0 + j];
  #pragma unroll
  for (int k = 0; k < 4; k++) {
    int sp = s - 3 + k;
    if (sp < 0) continue;
    s16x8 v = *(const s16x8*)&zx[(size_t)(row - 3 + k) * 2320 + 1024 + c0];
    #pragma unroll
    for (int j = 0; j < 8; j++) acc[j] += bf2f(v[j]) * cw[(c0 + j) * 4 + k];
  }
  #pragma unroll
  for (int j = 0; j < 8; j++)
    xc[(size_t)row * 1280 + c0 + j] = silu_f(acc[j]);
}

// ---------------------------------------------------------------------------
// SSM scan v7: p-split 2-way (1024 blocks = 4/CU), 8-step chunks, 24KiB LDS.
// Each block owns 32 of 64 p-rows for one (b,h); identical per-(p,n) math.
// ---------------------------------------------------------------------------
__global__ __launch_bounds__(256) void scan_kernel(
    const float* __restrict__ dt, const float* __restrict__ dA,
    const float* __restrict__ xc, float* __restrict__ y)
{
  __shared__ float sdA[512];
  __shared__ float sdt[512];
  __shared__ float sBC[2][2048];
  __shared__ float sX[2][512];
  const int bx = blockIdx.x;
  const int b = bx >> 5, h = (bx >> 1) & 15, psplit = bx & 1;
  const int t = threadIdx.x;
  const int pr = t >> 4, nc = t & 15;      // 16 p-groups x 16 n-lanes
  const int pgA = psplit * 32 + pr;        // rows [0,16) or [32,48)
  const int pgB = pgA + 16;                // rows [16,32) or [48,64)
  const float* xcb = xc + (size_t)(b * 512) * 1280;

  const int ck  = t & 63;
  const int sck = ck ^ ((ck >> 3) & 1);
  const int a0 = nc * 2,      pa0 = (a0 ^ ((a0 >> 3) & 1)) * 4;
  const int a1 = nc * 2 + 1,  pa1 = (a1 ^ ((a1 >> 3) & 1)) * 4;
  const int a2 = nc * 2 + 32, pa2 = (a2 ^ ((a2 >> 3) & 1)) * 4;
  const int a3 = nc * 2 + 33, pa3 = (a3 ^ ((a3 >> 3) & 1)) * 4;

  sdA[t] = dA[(b * 512 + t) * 16 + h];
  sdA[t + 256] = dA[(b * 512 + t + 256) * 16 + h];
  sdt[t] = dt[(b * 512 + t) * 16 + h];
  sdt[t + 256] = dt[(b * 512 + t + 256) * 16 + h];
  #pragma unroll
  for (int i = 0; i < 2; i++) {
    int idx = t + 256 * i;
    int row = idx >> 6;                     // wave-uniform
    glds16f(xcb + (size_t)row * 1280 + 1024 + sck * 4, &sBC[0][idx * 4]);
    glds4f (xcb + (size_t)row * 1280 + h * 64 + ck,    &sX[0][idx]);
  }
  __syncthreads();

  float hA[8] = {0,0,0,0,0,0,0,0}, hB[8] = {0,0,0,0,0,0,0,0};
  float* yb0 = y + (size_t)(b * 512) * 1024 + h * 64;

  for (int c = 0; c < 64; ++c) {
    const int cur = c & 1;
    if (c < 63) {
      const float* src = xcb + (size_t)((c + 1) * 8) * 1280;
      #pragma unroll
      for (int i = 0; i < 2; i++) {
        int idx = t + 256 * i;
        int row = idx >> 6;
        glds16f(src + (size_t)row * 1280 + 1024 + sck * 4, &sBC[cur ^ 1][idx * 4]);
        glds4f (src + (size_t)row * 1280 + h * 64 + ck,    &sX[cur ^ 1][idx]);
      }
    }
    const float* bc = sBC[cur];
    const float* sx = sX[cur];
    const int sg0 = c * 8;
    #pragma unroll 2
    for (int st = 0; st < 8; ++st) {
      float dA0 = sdA[sg0 + st];
      float dt0 = sdt[sg0 + st];
      float xA = sx[st * 64 + pgA];
      float xB = sx[st * 64 + pgB];
      const float* base = bc + st * 256;
      f32x4 b0 = *(const f32x4*)(base + pa0);
      f32x4 b1 = *(const f32x4*)(base + pa1);
      f32x4 c0 = *(const f32x4*)(base + pa2);
      f32x4 c1 = *(const f32x4*)(base + pa3);
      float cxA = dt0 * xA, cxB = dt0 * xB;
      float psA = 0.f, psB = 0.f;
      #pragma unroll
      for (int j = 0; j < 4; j++) {
        hA[j] = dA0 * hA[j] + cxA * b0[j];  psA += hA[j] * c0[j];
        hB[j] = dA0 * hB[j] + cxB * b0[j];  psB += hB[j] * c0[j];
      }
      #pragma unroll
      for (int j = 0; j < 4; j++) {
        hA[4+j] = dA0 * hA[4+j] + cxA * b1[j];  psA += hA[4+j] * c1[j];
        hB[4+j] = dA0 * hB[4+j] + cxB * b1[j];  psB += hB[4+j] * c1[j];
      }
      psA += __shfl_xor(psA, 1); psB += __shfl_xor(psB, 1);
      psA += __shfl_xor(psA, 2); psB += __shfl_xor(psB, 2);
      psA += __shfl_xor(psA, 4); psB += __shfl_xor(psB, 4);
      psA += __shfl_xor(psA, 8); psB += __shfl_xor(psB, 8);
      if (nc == 0) {
        float* yr = yb0 + (size_t)(sg0 + st) * 1024;
        yr[pgA] = psA;
        yr[pgB] = psB;
      }
    }
    __syncthreads();
  }
}

__global__ __launch_bounds__(256) void ycombine_kernel(
    const float* __restrict__ y, const float* __restrict__ xc,
    const short* __restrict__ zx, const float* __restrict__ Dskip,
    const float* __restrict__ norm_g, short* __restrict__ ybf)
{
  const int t = threadIdx.x;
  const int lane = t & 63, w = t >> 6;
  const int row = blockIdx.x * 4 + w;
  const float* yp = y + (size_t)row * 1024;
  const float* xp = xc + (size_t)row * 1280;
  const short* zp = zx + (size_t)row * 2320;

  float o[16];
  float ss = 0.f;
  #pragma unroll
  for (int i = 0; i < 4; i++) {
    int c = lane + 64 * i;
    int c4 = c * 4;
    f32x4 yv = *(const f32x4*)(yp + c4);
    f32x4 xv = *(const f32x4*)(xp + c4);
    s16x4 zv = *(const s16x4*)(zp + c4);
    float dsk = Dskip[c >> 4];
    #pragma unroll
    for (int j = 0; j < 4; j++) {
      float v = (yv[j] + dsk * xv[j]) * silu_f(bf2f(zv[j]));
      o[i * 4 + j] = v; ss += v * v;
    }
  }
  ss = wave_reduce_sum(ss) * (1.f / 1024.f);
  float rs = rsqrtf(ss + 1e-5f);
  #pragma unroll
  for (int i = 0; i < 4; i++) {
    int c4 = (lane + 64 * i) * 4;
    f32x4 gv = *(const f32x4*)(norm_g + c4);
    s16x4 ov;
    #pragma unroll
    for (int j = 0; j < 4; j++) ov[j] = f2bf(o[i * 4 + j] * rs * gv[j]);
    *(s16x4*)(ybf + (size_t)row * 1024 + c4) = ov;
  }
}

__global__ void pool2_kernel(const float* __restrict__ outb, float* __restrict__ part)
{
  int b = blockIdx.x, ch = blockIdx.y, d = threadIdx.x;
  const float* p = outb + ((size_t)(b * 512 + ch * 64)) * 512 + d;
  float s = 0.f;
  #pragma unroll 8
  for (int i = 0; i < 64; i++) s += p[(size_t)i * 512];
  part[(b * 8 + ch) * 512 + d] = s;
}

__global__ void poolred_kernel(const float* __restrict__ part, float* __restrict__ pooled)
{
  int b = blockIdx.x, d = threadIdx.x;
  float s = 0.f;
  #pragma unroll
  for (int c = 0; c < 8; c++) s += part[(b * 8 + c) * 512 + d];
  pooled[b * 512 + d] = s * (1.f / 512.f);
}

__global__ void finalproj_kernel(const float* __restrict__ pooled,
                                 const float* __restrict__ Wp,
                                 const float* __restrict__ bp,
                                 float* __restrict__ out)
{
  int b = blockIdx.x, n = threadIdx.x;
  float acc = bp[n];
  for (int k = 0; k < 512; k++) acc += pooled[b * 512 + k] * Wp[k * 256 + n];
  out[b * 256 + n] = acc;
}

// ---------------------------------------------------------------------------
// Host
// ---------------------------------------------------------------------------
extern "C" void kernel_launch(void* const* d_in, const int* in_sizes, int n_in,
                              void* d_out, int out_size, void* d_ws, size_t ws_size,
                              hipStream_t stream)
{
  const int*   ids      = (const int*)d_in[0];
  const int*   amask    = (const int*)d_in[1];
  const float* tok_emb  = (const float*)d_in[2];
  const float* pos_emb  = (const float*)d_in[3];
  const float* type_emb = (const float*)d_in[4];
  const float* emb_g    = (const float*)d_in[5];
  const float* emb_b    = (const float*)d_in[6];
  const float* Wq = (const float*)d_in[7];   const float* bq = (const float*)d_in[8];
  const float* Wk = (const float*)d_in[9];   const float* bk = (const float*)d_in[10];
  const float* Wv = (const float*)d_in[11];  const float* bv = (const float*)d_in[12];
  const float* Wo = (const float*)d_in[13];  const float* bo = (const float*)d_in[14];
  const float* ln1g = (const float*)d_in[15]; const float* ln1b = (const float*)d_in[16];
  const float* Wf1 = (const float*)d_in[17]; const float* bf1 = (const float*)d_in[18];
  const float* Wf2 = (const float*)d_in[19]; const float* bf2 = (const float*)d_in[20];
  const float* ln2g = (const float*)d_in[21]; const float* ln2b = (const float*)d_in[22];
  const float* W_pb = (const float*)d_in[23]; const float* b_pb = (const float*)d_in[24];
  const float* W_in = (const float*)d_in[25];
  const float* conv_w = (const float*)d_in[26]; const float* conv_b = (const float*)d_in[27];
  const float* dt_bias = (const float*)d_in[28]; const float* A_log = (const float*)d_in[29];
  const float* Dskip = (const float*)d_in[30]; const float* norm_g = (const float*)d_in[31];
  const float* W_out = (const float*)d_in[32];
  const float* W_proj = (const float*)d_in[33]; const float* b_proj = (const float*)d_in[34];

  char* base = (char*)d_ws;
  const size_t o_xb   = 0;
  const size_t o_wall = 25165824;
  const size_t o_bv   = o_wall + 169869312;
  const size_t o_cb   = o_bv + 65536;
  const size_t o_gtb  = o_cb + 131072;
  const size_t o_qkv  = o_gtb + 25165824;
  const size_t o_ao   = o_qkv + 75497472;
  const size_t o_ff   = o_ao + 25165824;
  const size_t bert_end = o_ff + 100663296;        // 421,724,160
  const size_t o_hw  = o_wall;
  const size_t o_xm  = o_hw + 4325376;
  const size_t o_zx  = o_xm + 16777216;
  const size_t o_xc  = o_zx + 76021760;
  const size_t o_dt  = o_xc + 83886080;
  const size_t o_dA  = o_dt + 1048576;
  const size_t o_y   = o_dA + 1048576;
  const size_t o_ybf = o_y  + 67108864;
  const size_t o_ob  = o_ybf + 33554432;
  const size_t o_pl  = o_ob + 33554432;
  const size_t o_pp  = o_pl + 65536;
  const size_t head_end = o_pp + 524288;
  const size_t need = (head_end > bert_end ? head_end : bert_end);
  if (ws_size < need) return;

  short* xb   = (short*)(base + o_xb);
  short* wall = (short*)(base + o_wall);
  float* bvp  = (float*)(base + o_bv);
  float* cbia = (float*)(base + o_cb);
  short* gtb  = (short*)(base + o_gtb);
  short* qkvb = (short*)(base + o_qkv);
  short* aob  = (short*)(base + o_ao);
  short* ffb  = (short*)(base + o_ff);
  short* hw   = (short*)(base + o_hw);
  short* xm   = (short*)(base + o_xm);
  short* zx   = (short*)(base + o_zx);
  float* xc   = (float*)(base + o_xc);
  float* dtb  = (float*)(base + o_dt);
  float* dAb  = (float*)(base + o_dA);
  float* yb   = (float*)(base + o_y);
  short* ybf  = (short*)(base + o_ybf);
  float* ob   = (float*)(base + o_ob);
  float* pl   = (float*)(base + o_pl);
  float* pp   = (float*)(base + o_pp);

  short* w_pbt  = hw;
  short* w_int  = w_pbt + 393216;
  short* w_outt = w_int + 1245184;

  const int M = 16384;
  dim3 blk(256);

  transconv4_all_kernel<<<dim3(24, 24, 48), blk, 0, stream>>>(Wq, Wk, Wv, Wo, wall);
  transconv_f1_all_kernel<<<dim3(96, 24, 12), blk, 0, stream>>>(Wf1, wall);
  transconv_f2_all_kernel<<<dim3(24, 96, 12), blk, 0, stream>>>(Wf2, wall);
  concatbias_all_kernel<<<108, 256, 0, stream>>>(bq, bk, bv, cbia);

  maskbias_kernel<<<64, 256, 0, stream>>>(amask, bvp);
  embed_ln_kernel<<<16384, 256, 0, stream>>>(ids, tok_emb, pos_emb, type_emb,
                                             emb_g, emb_b, xb);

  for (int l = 0; l < 12; l++) {
    short* wl = wall + (size_t)l * 7077888;
    gemm3<1, 2, 128><<<dim3(18, 128), 512, 0, stream>>>(xb, wl, cbia + l * 2304, qkvb, M, 2304, 768);
    attn_kernel<<<dim3(4, 12, 32), 512, 0, stream>>>(qkvb, bvp, aob);
    gemm3<1, 2, 128><<<dim3(6, 128), 512, 0, stream>>>(aob, wl + 3ull * 589824, bo + l * 768, gtb, M, 768, 768);
    add_ln_kernel<<<4096, 256, 0, stream>>>(xb, gtb, ln1g + l * 768, ln1b + l * 768);
    gemm3<2, 2, 128><<<dim3(24, 128), 512, 0, stream>>>(xb, wl + 2359296, bf1 + l * 3072, ffb, M, 3072, 768);
    gemm3<1, 2, 128><<<dim3(6, 128), 512, 0, stream>>>(ffb, wl + 4718592, bf2 + l * 768, gtb, M, 768, 3072);
    add_ln_kernel<<<4096, 256, 0, stream>>>(xb, gtb, ln2g + l * 768, ln2b + l * 768);
  }

  // ---- head ----
  transconv_kernel<<<dim3(16, 24), blk, 0, stream>>>(W_pb, w_pbt, 768, 512, 512);
  gemm3<1, 2, 128><<<dim3(4, 128), 512, 0, stream>>>(xb, w_pbt, b_pb, xm, M, 512, 768);
  transconv_kernel<<<dim3(76, 16), blk, 0, stream>>>(W_in, w_int, 512, 2320, 2432);
  gemm3<1, 2, 128><<<dim3(19, 128), 512, 0, stream>>>(xm, w_int, nullptr, zx, M, 2320, 512);
  dtda_kernel<<<1024, 256, 0, stream>>>(zx, dt_bias, A_log, dtb, dAb);
  conv2_kernel<<<10240, 256, 0, stream>>>(zx, conv_w, conv_b, xc);
  scan_kernel<<<1024, 256, 0, stream>>>(dtb, dAb, xc, yb);
  ycombine_kernel<<<4096, 256, 0, stream>>>(yb, xc, zx, Dskip, norm_g, ybf);
  transconv_kernel<<<dim3(16, 32), blk, 0, stream>>>(W_out, w_outt, 1024, 512, 512);
  gemm2<0><<<dim3(4, 128), blk, 0, stream>>>(ybf, w_outt, nullptr, ob, M, 512, 1024);
  pool2_kernel<<<dim3(32, 8), 512, 0, stream>>>(ob, pp);
  poolred_kernel<<<32, 512, 0, stream>>>(pp, pl);
  finalproj_kernel<<<32, 256, 0, stream>>>(pl, W_proj, b_proj, (float*)d_out);
}

// Round 25
// 5582.473 us; speedup vs baseline: 1.0061x; 1.0061x over previous
//
#include <hip/hip_runtime.h>
#include <hip/hip_bf16.h>

// ---------------------------------------------------------------------------
// ContrastiveMambaEncoder. Round 25: restore round-22 config verbatim —
// measured session best (5587 us). scan v6 (512 blocks); all BERT gemms
// gemm3<.,2,128> (2 blocks/CU); head gemms gemm2 (m97).
// ---------------------------------------------------------------------------

typedef __attribute__((ext_vector_type(4))) float f32x4;
typedef __attribute__((ext_vector_type(4))) short s16x4;
typedef __attribute__((ext_vector_type(8))) short s16x8;

#define DEV __device__ __forceinline__

DEV short f2bf(float f) {
  union { float f; unsigned u; } x; x.f = f;
  unsigned r = x.u + 0x7fffu + ((x.u >> 16) & 1u);
  return (short)(r >> 16);
}
DEV float bf2f(short h) {
  union { unsigned u; float f; } x; x.u = ((unsigned)(unsigned short)h) << 16;
  return x.f;
}
DEV float gelu_f(float x) {
  float u = 0.7978845608028654f * (x + 0.044715f * x * x * x);
  return 0.5f * x * (1.f + tanhf(u));
}
DEV float silu_f(float x) { return x / (1.f + __expf(-x)); }

DEV void glds16(const short* g, short* l) {
  __builtin_amdgcn_global_load_lds(
      (const __attribute__((address_space(1))) void*)g,
      (__attribute__((address_space(3))) void*)l, 16, 0, 0);
}
DEV void glds16f(const float* g, float* l) {
  __builtin_amdgcn_global_load_lds(
      (const __attribute__((address_space(1))) void*)g,
      (__attribute__((address_space(3))) void*)l, 16, 0, 0);
}
DEV void glds4f(const float* g, float* l) {
  __builtin_amdgcn_global_load_lds(
      (const __attribute__((address_space(1))) void*)g,
      (__attribute__((address_space(3))) void*)l, 4, 0, 0);
}

DEV float block_reduce_sum_256(float v, float* red) {
  #pragma unroll
  for (int o = 1; o < 64; o <<= 1) v += __shfl_xor(v, o);
  __syncthreads();
  if ((threadIdx.x & 63) == 0) red[threadIdx.x >> 6] = v;
  __syncthreads();
  return red[0] + red[1] + red[2] + red[3];
}

DEV float wave_reduce_sum(float v) {
  #pragma unroll
  for (int o = 1; o < 64; o <<= 1) v += __shfl_xor(v, o);
  return v;
}

// ---------------------------------------------------------------------------
// Weight prep (batched over all 12 layers).
// ---------------------------------------------------------------------------
__global__ __launch_bounds__(256) void transconv4_all_kernel(
    const float* __restrict__ Wq, const float* __restrict__ Wk,
    const float* __restrict__ Wv, const float* __restrict__ Wo,
    short* __restrict__ Wall)
{
  int l = blockIdx.z >> 2, which = blockIdx.z & 3;
  const float* Wb = (which == 0) ? Wq : (which == 1) ? Wk : (which == 2) ? Wv : Wo;
  const float* W = Wb + (size_t)l * 589824;
  short* Wtz = Wall + (size_t)l * 7077888 + (size_t)which * 589824;
  __shared__ float tile[32][33];
  int tx = threadIdx.x & 31, ty = threadIdx.x >> 5;
  int n0 = blockIdx.x * 32, k0 = blockIdx.y * 32;
  #pragma unroll
  for (int i = 0; i < 4; i++)
    tile[ty + i * 8][tx] = W[(size_t)(k0 + ty + i * 8) * 768 + n0 + tx];
  __syncthreads();
  #pragma unroll
  for (int i = 0; i < 4; i++)
    Wtz[(size_t)(n0 + ty + i * 8) * 768 + k0 + tx] = f2bf(tile[tx][ty + i * 8]);
}

__global__ __launch_bounds__(256) void transconv_f1_all_kernel(
    const float* __restrict__ Wf1, short* __restrict__ Wall)
{
  int l = blockIdx.z;
  const float* W = Wf1 + (size_t)l * 2359296;
  short* Wt = Wall + (size_t)l * 7077888 + 2359296;
  __shared__ float tile[32][33];
  int tx = threadIdx.x & 31, ty = threadIdx.x >> 5;
  int n0 = blockIdx.x * 32, k0 = blockIdx.y * 32;
  #pragma unroll
  for (int i = 0; i < 4; i++)
    tile[ty + i * 8][tx] = W[(size_t)(k0 + ty + i * 8) * 3072 + n0 + tx];
  __syncthreads();
  #pragma unroll
  for (int i = 0; i < 4; i++)
    Wt[(size_t)(n0 + ty + i * 8) * 768 + k0 + tx] = f2bf(tile[tx][ty + i * 8]);
}

__global__ __launch_bounds__(256) void transconv_f2_all_kernel(
    const float* __restrict__ Wf2, short* __restrict__ Wall)
{
  int l = blockIdx.z;
  const float* W = Wf2 + (size_t)l * 2359296;
  short* Wt = Wall + (size_t)l * 7077888 + 4718592;
  __shared__ float tile[32][33];
  int tx = threadIdx.x & 31, ty = threadIdx.x >> 5;
  int n0 = blockIdx.x * 32, k0 = blockIdx.y * 32;
  #pragma unroll
  for (int i = 0; i < 4; i++)
    tile[ty + i * 8][tx] = W[(size_t)(k0 + ty + i * 8) * 768 + n0 + tx];
  __syncthreads();
  #pragma unroll
  for (int i = 0; i < 4; i++)
    Wt[(size_t)(n0 + ty + i * 8) * 3072 + k0 + tx] = f2bf(tile[tx][ty + i * 8]);
}

__global__ __launch_bounds__(256) void transconv_kernel(
    const float* __restrict__ W, short* __restrict__ Wt,
    int K, int N, int Npad)
{
  __shared__ float tile[32][33];
  int tx = threadIdx.x & 31, ty = threadIdx.x >> 5;
  int n0 = blockIdx.x * 32, k0 = blockIdx.y * 32;
  #pragma unroll
  for (int i = 0; i < 4; i++) {
    int k = k0 + ty + i * 8, n = n0 + tx;
    tile[ty + i * 8][tx] = (k < K && n < N) ? W[(size_t)k * N + n] : 0.f;
  }
  __syncthreads();
  #pragma unroll
  for (int i = 0; i < 4; i++) {
    int n = n0 + ty + i * 8, k = k0 + tx;
    if (n < Npad && k < K)
      Wt[(size_t)n * K + k] = f2bf(tile[tx][ty + i * 8]);
  }
}

__global__ void concatbias_all_kernel(const float* __restrict__ bq,
                                      const float* __restrict__ bk,
                                      const float* __restrict__ bv,
                                      float* __restrict__ cb)
{
  int i = blockIdx.x * 256 + threadIdx.x;
  if (i >= 12 * 2304) return;
  int l = i / 2304, c = i - l * 2304;
  cb[i] = (c < 768) ? bq[l * 768 + c]
        : (c < 1536) ? bk[l * 768 + c - 768] : bv[l * 768 + c - 1536];
}

// ---------------------------------------------------------------------------
// gemm3: round-9 counted-vmcnt schedule; BM template param.
// ---------------------------------------------------------------------------
template<int OUTMODE, int WN, int BM>
__global__ __launch_bounds__(512) void gemm3(
    const short* __restrict__ A, const short* __restrict__ Bt,
    const float* __restrict__ bias, short* __restrict__ Cout,
    int M, int N, int K)
{
  constexpr int BN = 64 * WN;
  constexpr int MI = (BM * WN) / 128;
  constexpr int WROWS = 16 * MI;
  constexpr int VMC = BM / 64 + BN / 64;
  __shared__ short As[2][BM * 64];
  __shared__ short Bs[2][BN * 64];
  const int t = threadIdx.x;
  const int lane = t & 63;
  const int lr = lane & 15, lg = lane >> 4;
  const int wid = t >> 6;
  const int wr = (WN == 4) ? (wid >> 2) : (wid >> 1);
  const int wc = (WN == 4) ? (wid & 3) : (wid & 1);

  const int nwg = gridDim.x * gridDim.y;
  const int lid = blockIdx.y * gridDim.x + blockIdx.x;
  const int xcd = lid & 7, rest = lid >> 3;
  const int qq = nwg >> 3, rr = nwg & 7;
  const int wgid = (xcd < rr ? xcd * (qq + 1) : rr * (qq + 1) + (xcd - rr) * qq) + rest;
  const int m0 = (wgid / gridDim.x) * BM;
  const int n0 = (wgid % gridDim.x) * BN;

  const short* Ab = A + (size_t)m0 * K;
  const short* Bb = Bt + (size_t)n0 * K;

  auto stage = [&](int buf, int k0) {
    #pragma unroll
    for (int i = 0; i < BM / 64; i++) {
      int idx = t + 512 * i;
      int row = idx >> 3, c = idx & 7;
      int cs = c ^ (row & 7);
      glds16(Ab + (size_t)row * K + k0 + cs * 8, &As[buf][idx * 8]);
    }
    #pragma unroll
    for (int i = 0; i < BN / 64; i++) {
      int idx = t + 512 * i;
      int row = idx >> 3, c = idx & 7;
      int cs = c ^ (row & 7);
      glds16(Bb + (size_t)row * K + k0 + cs * 8, &Bs[buf][idx * 8]);
    }
  };

  f32x4 acc[MI][4] = {};
  const int nt = K >> 6;

  stage(0, 0);
  stage(1, 64);

  for (int tt = 0; tt < nt; ++tt) {
    const int cur = tt & 1;
    if (tt + 1 < nt) {
      if constexpr (VMC == 8)      asm volatile("s_waitcnt vmcnt(8)" ::: "memory");
      else if constexpr (VMC == 6) asm volatile("s_waitcnt vmcnt(6)" ::: "memory");
      else                         asm volatile("s_waitcnt vmcnt(4)" ::: "memory");
    } else {
      asm volatile("s_waitcnt vmcnt(0)" ::: "memory");
    }
    __builtin_amdgcn_s_barrier();
    asm volatile("" ::: "memory");
    __builtin_amdgcn_sched_barrier(0);

    s16x8 af[MI][2], bfr[4][2];
    #pragma unroll
    for (int mi = 0; mi < MI; mi++) {
      int row = wr * WROWS + mi * 16 + lr;
      #pragma unroll
      for (int ks = 0; ks < 2; ks++) {
        int ck = (ks * 4 + lg) ^ (lr & 7);
        af[mi][ks] = *(const s16x8*)&As[cur][row * 64 + ck * 8];
      }
    }
    #pragma unroll
    for (int ni = 0; ni < 4; ni++) {
      int row = wc * 64 + ni * 16 + lr;
      #pragma unroll
      for (int ks = 0; ks < 2; ks++) {
        int ck = (ks * 4 + lg) ^ (lr & 7);
        bfr[ni][ks] = *(const s16x8*)&Bs[cur][row * 64 + ck * 8];
      }
    }
    asm volatile("s_waitcnt lgkmcnt(0)" ::: "memory");
    __builtin_amdgcn_sched_barrier(0);
    __builtin_amdgcn_s_barrier();
    asm volatile("" ::: "memory");
    __builtin_amdgcn_sched_barrier(0);

    if (tt + 2 < nt) stage(cur, (tt + 2) * 64);

    __builtin_amdgcn_s_setprio(1);
    #pragma unroll
    for (int ks = 0; ks < 2; ks++)
      #pragma unroll
      for (int mi = 0; mi < MI; mi++)
        #pragma unroll
        for (int ni = 0; ni < 4; ni++)
          acc[mi][ni] = __builtin_amdgcn_mfma_f32_16x16x32_bf16(
              af[mi][ks], bfr[ni][ks], acc[mi][ni], 0, 0, 0);
    __builtin_amdgcn_s_setprio(0);
  }

  #pragma unroll
  for (int mi = 0; mi < MI; mi++) {
    int row = m0 + wr * WROWS + mi * 16 + lg * 4;
    #pragma unroll
    for (int ni = 0; ni < 4; ni++) {
      int col = n0 + wc * 64 + ni * 16 + lr;
      float bv = bias ? bias[col] : 0.f;
      #pragma unroll
      for (int r = 0; r < 4; r++) {
        float v = acc[mi][ni][r] + bv;
        if (OUTMODE == 2) v = gelu_f(v);
        Cout[(size_t)(row + r) * N + col] = f2bf(v);
      }
    }
  }
}

// ---------------------------------------------------------------------------
// GEMM (m97 structure) — head gemms.
// ---------------------------------------------------------------------------
template<int OUTMODE>
__global__ __launch_bounds__(256) void gemm2(
    const short* __restrict__ A, const short* __restrict__ Bt,
    const float* __restrict__ bias, void* __restrict__ Cout,
    int M, int N, int K)
{
  __shared__ short As[128 * 64];
  __shared__ short Bs[128 * 64];
  const int t = threadIdx.x;
  const int lane = t & 63;
  const int lr = lane & 15, lg = lane >> 4;
  const int wid = t >> 6, wm = wid >> 1, wn = wid & 1;

  const int nwg = gridDim.x * gridDim.y;
  const int lid = blockIdx.y * gridDim.x + blockIdx.x;
  const int xcd = lid & 7, rest = lid >> 3;
  const int qq = nwg >> 3, rr = nwg & 7;
  const int wgid = (xcd < rr ? xcd * (qq + 1) : rr * (qq + 1) + (xcd - rr) * qq) + rest;
  const int m0 = (wgid / gridDim.x) * 128;
  const int n0 = (wgid % gridDim.x) * 128;

  f32x4 acc[4][4] = {};
  const short* Ab = A + (size_t)m0 * K;
  const short* Bb = Bt + (size_t)n0 * K;

  for (int k0 = 0; k0 < K; k0 += 64) {
    __syncthreads();
    #pragma unroll
    for (int i = 0; i < 4; i++) {
      int idx = t + 256 * i;
      int row = idx >> 3, c = idx & 7;
      glds16(Ab + (size_t)row * K + k0 + c * 8, &As[idx * 8]);
    }
    #pragma unroll
    for (int i = 0; i < 4; i++) {
      int idx = t + 256 * i;
      int row = idx >> 3, c = idx & 7;
      glds16(Bb + (size_t)row * K + k0 + c * 8, &Bs[idx * 8]);
    }
    __syncthreads();
    #pragma unroll
    for (int ks = 0; ks < 2; ks++) {
      s16x8 af[4], bfr[4];
      #pragma unroll
      for (int mi = 0; mi < 4; mi++)
        af[mi] = *(const s16x8*)&As[(wm * 64 + mi * 16 + lr) * 64 + ks * 32 + lg * 8];
      #pragma unroll
      for (int ni = 0; ni < 4; ni++)
        bfr[ni] = *(const s16x8*)&Bs[(wn * 64 + ni * 16 + lr) * 64 + ks * 32 + lg * 8];
      #pragma unroll
      for (int mi = 0; mi < 4; mi++)
        #pragma unroll
        for (int ni = 0; ni < 4; ni++)
          acc[mi][ni] = __builtin_amdgcn_mfma_f32_16x16x32_bf16(
              af[mi], bfr[ni], acc[mi][ni], 0, 0, 0);
    }
  }

  #pragma unroll
  for (int mi = 0; mi < 4; mi++) {
    int row = m0 + wm * 64 + mi * 16 + lg * 4;
    #pragma unroll
    for (int ni = 0; ni < 4; ni++) {
      int col = n0 + wn * 64 + ni * 16 + lr;
      if (col >= N) continue;
      float bv = bias ? bias[col] : 0.f;
      #pragma unroll
      for (int r = 0; r < 4; r++) {
        float v = acc[mi][ni][r] + bv;
        if (OUTMODE == 2) v = gelu_f(v);
        size_t off = (size_t)(row + r) * N + col;
        if (OUTMODE == 0) ((float*)Cout)[off] = v;
        else              ((short*)Cout)[off] = f2bf(v);
      }
    }
  }
}

// ---------------------------------------------------------------------------
// Flash attention (QBLK=128, constant-shift softmax).
// ---------------------------------------------------------------------------
#define LDQ 2304
__global__ __launch_bounds__(512) void attn_kernel(
    const short* __restrict__ QKV, const float* __restrict__ biasv,
    short* __restrict__ O)
{
  __shared__ short Ks[64 * 72];
  __shared__ short Vt[64 * 68];
  __shared__ float bsh[64];
  const int t = threadIdx.x;
  const int lane = t & 63, wid = t >> 6;
  const int lr = lane & 15, lg = lane >> 4;
  const int b = blockIdx.z, h = blockIdx.y, q0 = blockIdx.x * 128;
  const float scale = 0.125f;

  s16x8 qf8[2];
  {
    const short* qp = QKV + (size_t)(b * 512 + q0 + wid * 16 + lr) * LDQ + h * 64;
    qf8[0] = *(const s16x8*)(qp + lg * 8);
    qf8[1] = *(const s16x8*)(qp + 32 + lg * 8);
  }

  f32x4 ot[4] = {};
  float lrun = 0.f;

  for (int kv0 = 0; kv0 < 512; kv0 += 64) {
    __syncthreads();
    {
      int row = t >> 3, c8 = (t & 7) * 8;
      *(s16x8*)&Ks[row * 72 + c8] =
          *(const s16x8*)(QKV + (size_t)(b * 512 + kv0 + row) * LDQ + 768 + h * 64 + c8);
    }
    {
      int kk = t & 63, dh = t >> 6;
      const short* vp = QKV + (size_t)(b * 512 + kv0 + kk) * LDQ + 1536 + h * 64 + dh * 8;
      s16x8 v0 = *(const s16x8*)vp;
      #pragma unroll
      for (int i = 0; i < 8; i++) Vt[(dh * 8 + i) * 68 + kk] = v0[i];
    }
    if (t < 64) bsh[t] = biasv[b * 512 + kv0 + t];
    __syncthreads();

    f32x4 st[4] = {};
    #pragma unroll
    for (int ks = 0; ks < 2; ks++) {
      #pragma unroll
      for (int a = 0; a < 4; a++) {
        s16x8 kf = *(const s16x8*)&Ks[(a * 16 + lr) * 72 + ks * 32 + lg * 8];
        st[a] = __builtin_amdgcn_mfma_f32_16x16x32_bf16(kf, qf8[ks], st[a], 0, 0, 0);
      }
    }
    float p[16];
    float rsum = 0.f;
    #pragma unroll
    for (int a = 0; a < 4; a++)
      #pragma unroll
      for (int r = 0; r < 4; r++) {
        float v = __expf(st[a][r] * scale + bsh[a * 16 + lg * 4 + r]);
        p[a * 4 + r] = v;
        rsum += v;
      }
    rsum += __shfl_xor(rsum, 16);
    rsum += __shfl_xor(rsum, 32);
    lrun += rsum;
    s16x4 ptf[4];
    #pragma unroll
    for (int ks = 0; ks < 4; ks++) {
      s16x4 f;
      #pragma unroll
      for (int j = 0; j < 4; j++) f[j] = f2bf(p[ks * 4 + j]);
      ptf[ks] = f;
    }
    #pragma unroll
    for (int ks = 0; ks < 4; ks++) {
      #pragma unroll
      for (int d = 0; d < 4; d++) {
        s16x4 vf = *(const s16x4*)&Vt[(d * 16 + lr) * 68 + ks * 16 + lg * 4];
        ot[d] = __builtin_amdgcn_mfma_f32_16x16x16bf16_1k(vf, ptf[ks], ot[d], 0, 0, 0);
      }
    }
  }

  float inv = 1.f / lrun;
  short* op = O + (size_t)(b * 512 + q0 + wid * 16 + lr) * 768 + h * 64;
  #pragma unroll
  for (int d = 0; d < 4; d++) {
    s16x4 w;
    #pragma unroll
    for (int r = 0; r < 4; r++) w[r] = f2bf(ot[d][r] * inv);
    *(s16x4*)(op + d * 16 + lg * 4) = w;
  }
}

// ---------------------------------------------------------------------------
// Elementwise / norm / head kernels
// ---------------------------------------------------------------------------
__global__ void maskbias_kernel(const int* __restrict__ mask, float* __restrict__ biasv) {
  int i = blockIdx.x * 256 + threadIdx.x;
  if (i < 32 * 512) biasv[i] = mask[i] > 0 ? -8.0f : -1e9f;
}

__global__ __launch_bounds__(256) void embed_ln_kernel(
    const int* __restrict__ ids, const float* __restrict__ tok,
    const float* __restrict__ pos, const float* __restrict__ typ,
    const float* __restrict__ g, const float* __restrict__ bta,
    short* __restrict__ xb)
{
  __shared__ float red[4];
  int row = blockIdx.x, s = row & 511, t = threadIdx.x;
  int id = ids[row];
  float v[3], sum = 0.f;
  #pragma unroll
  for (int i = 0; i < 3; i++) {
    int c = t + 256 * i;
    float e = tok[(size_t)id * 768 + c] + pos[s * 768 + c] + typ[c];
    v[i] = e; sum += e;
  }
  float mean = block_reduce_sum_256(sum, red) * (1.f / 768.f);
  float var = 0.f;
  #pragma unroll
  for (int i = 0; i < 3; i++) { float d = v[i] - mean; var += d * d; }
  var = block_reduce_sum_256(var, red) * (1.f / 768.f);
  float rstd = rsqrtf(var + 1e-12f);
  #pragma unroll
  for (int i = 0; i < 3; i++) {
    int c = t + 256 * i;
    float o = (v[i] - mean) * rstd * g[c] + bta[c];
    xb[(size_t)row * 768 + c] = f2bf(o);
  }
}

__global__ __launch_bounds__(256) void add_ln_kernel(
    short* __restrict__ xb, const short* __restrict__ delta,
    const float* __restrict__ g, const float* __restrict__ bta)
{
  const int t = threadIdx.x;
  const int lane = t & 63, w = t >> 6;
  const int row = blockIdx.x * 4 + w;
  short* xp = xb + (size_t)row * 768;
  const short* dp = delta + (size_t)row * 768;

  float e[12];
  float sum = 0.f;
  #pragma unroll
  for (int i = 0; i < 3; i++) {
    int c4 = (lane + 64 * i) * 4;
    s16x4 xv = *(const s16x4*)(xp + c4);
    s16x4 dv = *(const s16x4*)(dp + c4);
    #pragma unroll
    for (int j = 0; j < 4; j++) {
      float v = bf2f(xv[j]) + bf2f(dv[j]);
      e[i * 4 + j] = v; sum += v;
    }
  }
  float mean = wave_reduce_sum(sum) * (1.f / 768.f);
  float var = 0.f;
  #pragma unroll
  for (int i = 0; i < 12; i++) { float d = e[i] - mean; var += d * d; }
  var = wave_reduce_sum(var) * (1.f / 768.f);
  float rstd = rsqrtf(var + 1e-12f);
  #pragma unroll
  for (int i = 0; i < 3; i++) {
    int c4 = (lane + 64 * i) * 4;
    f32x4 gv = *(const f32x4*)(g + c4);
    f32x4 bv = *(const f32x4*)(bta + c4);
    s16x4 o;
    #pragma unroll
    for (int j = 0; j < 4; j++)
      o[j] = f2bf((e[i * 4 + j] - mean) * rstd * gv[j] + bv[j]);
    *(s16x4*)(xp + c4) = o;
  }
}

__global__ void dtda_kernel(const short* __restrict__ zx,
                            const float* __restrict__ dt_bias,
                            const float* __restrict__ A_log,
                            float* __restrict__ dt, float* __restrict__ dA)
{
  int i = blockIdx.x * 256 + threadIdx.x;
  if (i >= 16384 * 16) return;
  int row = i >> 4, h = i & 15;
  float x = bf2f(zx[(size_t)row * 2320 + 2304 + h]) + dt_bias[h];
  float sp = (x > 20.f) ? x : log1pf(__expf(x));
  float a = -__expf(A_log[h]);
  dt[i] = sp;
  dA[i] = __expf(sp * a);
}

__global__ __launch_bounds__(256) void conv2_kernel(
    const short* __restrict__ zx, const float* __restrict__ cw,
    const float* __restrict__ cb, float* __restrict__ xc)
{
  int gid = blockIdx.x * 256 + threadIdx.x;
  int row = gid / 160, cg = gid - row * 160;
  if (row >= 16384) return;
  int s = row & 511, c0 = cg * 8;
  float acc[8];
  #pragma unroll
  for (int j = 0; j < 8; j++) acc[j] = cb[c0 + j];
  #pragma unroll
  for (int k = 0; k < 4; k++) {
    int sp = s - 3 + k;
    if (sp < 0) continue;
    s16x8 v = *(const s16x8*)&zx[(size_t)(row - 3 + k) * 2320 + 1024 + c0];
    #pragma unroll
    for (int j = 0; j < 8; j++) acc[j] += bf2f(v[j]) * cw[(c0 + j) * 4 + k];
  }
  #pragma unroll
  for (int j = 0; j < 8; j++)
    xc[(size_t)row * 1280 + c0 + j] = silu_f(acc[j]);
}

// SSM scan v6: 256 threads, 4 p-rows/thread.
__global__ __launch_bounds__(256) void scan_kernel(
    const float* __restrict__ dt, const float* __restrict__ dA,
    const float* __restrict__ xc, float* __restrict__ y)
{
  __shared__ float sdA[512];
  __shared__ float sdt[512];
  __shared__ float sBC[2][4096];
  __shared__ float sX[2][1024];
  const int b = blockIdx.x >> 4, h = blockIdx.x & 15;
  const int t = threadIdx.x;
  const int p4 = t >> 4, nc = t & 15;
  const float* xcb = xc + (size_t)(b * 512) * 1280;

  const int st_s = t >> 6;
  const int ck   = t & 63;
  const int sck  = ck ^ ((ck >> 3) & 1);
  const int a0 = nc * 2,      pa0 = (a0 ^ ((a0 >> 3) & 1)) * 4;
  const int a1 = nc * 2 + 1,  pa1 = (a1 ^ ((a1 >> 3) & 1)) * 4;
  const int a2 = nc * 2 + 32, pa2 = (a2 ^ ((a2 >> 3) & 1)) * 4;
  const int a3 = nc * 2 + 33, pa3 = (a3 ^ ((a3 >> 3) & 1)) * 4;

  sdA[t] = dA[(b * 512 + t) * 16 + h];
  sdA[t + 256] = dA[(b * 512 + t + 256) * 16 + h];
  sdt[t] = dt[(b * 512 + t) * 16 + h];
  sdt[t + 256] = dt[(b * 512 + t + 256) * 16 + h];
  #pragma unroll
  for (int i = 0; i < 4; i++) {
    glds16f(xcb + (size_t)(st_s + 4 * i) * 1280 + 1024 + sck * 4, &sBC[0][(t + 256 * i) * 4]);
    glds4f (xcb + (size_t)(st_s + 4 * i) * 1280 + h * 64 + ck,    &sX[0][t + 256 * i]);
  }
  __syncthreads();

  float hA[8] = {0,0,0,0,0,0,0,0}, hB[8] = {0,0,0,0,0,0,0,0};
  float hC[8] = {0,0,0,0,0,0,0,0}, hD[8] = {0,0,0,0,0,0,0,0};
  float* yb0 = y + (size_t)(b * 512) * 1024 + h * 64;

  for (int c = 0; c < 32; ++c) {
    const int cur = c & 1;
    if (c < 31) {
      const float* src = xcb + (size_t)((c + 1) * 16) * 1280;
      #pragma unroll
      for (int i = 0; i < 4; i++) {
        glds16f(src + (size_t)(st_s + 4 * i) * 1280 + 1024 + sck * 4, &sBC[cur ^ 1][(t + 256 * i) * 4]);
        glds4f (src + (size_t)(st_s + 4 * i) * 1280 + h * 64 + ck,    &sX[cur ^ 1][t + 256 * i]);
      }
    }
    const float* bc = sBC[cur];
    const float* sx = sX[cur];
    const int sg0 = c * 16;
    #pragma unroll 2
    for (int st = 0; st < 16; ++st) {
      float dA0 = sdA[sg0 + st];
      float dt0 = sdt[sg0 + st];
      float xA = sx[st * 64 + p4];
      float xB = sx[st * 64 + p4 + 16];
      float xC = sx[st * 64 + p4 + 32];
      float xD = sx[st * 64 + p4 + 48];
      const float* base = bc + st * 256;
      f32x4 b0 = *(const f32x4*)(base + pa0);
      f32x4 b1 = *(const f32x4*)(base + pa1);
      f32x4 c0 = *(const f32x4*)(base + pa2);
      f32x4 c1 = *(const f32x4*)(base + pa3);
      float cxA = dt0 * xA, cxB = dt0 * xB, cxC = dt0 * xC, cxD = dt0 * xD;
      float psA = 0.f, psB = 0.f, psC = 0.f, psD = 0.f;
      #pragma unroll
      for (int j = 0; j < 4; j++) {
        hA[j] = dA0 * hA[j] + cxA * b0[j];  psA += hA[j] * c0[j];
        hB[j] = dA0 * hB[j] + cxB * b0[j];  psB += hB[j] * c0[j];
        hC[j] = dA0 * hC[j] + cxC * b0[j];  psC += hC[j] * c0[j];
        hD[j] = dA0 * hD[j] + cxD * b0[j];  psD += hD[j] * c0[j];
      }
      #pragma unroll
      for (int j = 0; j < 4; j++) {
        hA[4+j] = dA0 * hA[4+j] + cxA * b1[j];  psA += hA[4+j] * c1[j];
        hB[4+j] = dA0 * hB[4+j] + cxB * b1[j];  psB += hB[4+j] * c1[j];
        hC[4+j] = dA0 * hC[4+j] + cxC * b1[j];  psC += hC[4+j] * c1[j];
        hD[4+j] = dA0 * hD[4+j] + cxD * b1[j];  psD += hD[4+j] * c1[j];
      }
      psA += __shfl_xor(psA, 1); psB += __shfl_xor(psB, 1);
      psC += __shfl_xor(psC, 1); psD += __shfl_xor(psD, 1);
      psA += __shfl_xor(psA, 2); psB += __shfl_xor(psB, 2);
      psC += __shfl_xor(psC, 2); psD += __shfl_xor(psD, 2);
      psA += __shfl_xor(psA, 4); psB += __shfl_xor(psB, 4);
      psC += __shfl_xor(psC, 4); psD += __shfl_xor(psD, 4);
      psA += __shfl_xor(psA, 8); psB += __shfl_xor(psB, 8);
      psC += __shfl_xor(psC, 8); psD += __shfl_xor(psD, 8);
      if (nc == 0) {
        float* yr = yb0 + (size_t)(sg0 + st) * 1024;
        yr[p4]      = psA;
        yr[p4 + 16] = psB;
        yr[p4 + 32] = psC;
        yr[p4 + 48] = psD;
      }
    }
    __syncthreads();
  }
}

__global__ __launch_bounds__(256) void ycombine_kernel(
    const float* __restrict__ y, const float* __restrict__ xc,
    const short* __restrict__ zx, const float* __restrict__ Dskip,
    const float* __restrict__ norm_g, short* __restrict__ ybf)
{
  const int t = threadIdx.x;
  const int lane = t & 63, w = t >> 6;
  const int row = blockIdx.x * 4 + w;
  const float* yp = y + (size_t)row * 1024;
  const float* xp = xc + (size_t)row * 1280;
  const short* zp = zx + (size_t)row * 2320;

  float o[16];
  float ss = 0.f;
  #pragma unroll
  for (int i = 0; i < 4; i++) {
    int c = lane + 64 * i;
    int c4 = c * 4;
    f32x4 yv = *(const f32x4*)(yp + c4);
    f32x4 xv = *(const f32x4*)(xp + c4);
    s16x4 zv = *(const s16x4*)(zp + c4);
    float dsk = Dskip[c >> 4];
    #pragma unroll
    for (int j = 0; j < 4; j++) {
      float v = (yv[j] + dsk * xv[j]) * silu_f(bf2f(zv[j]));
      o[i * 4 + j] = v; ss += v * v;
    }
  }
  ss = wave_reduce_sum(ss) * (1.f / 1024.f);
  float rs = rsqrtf(ss + 1e-5f);
  #pragma unroll
  for (int i = 0; i < 4; i++) {
    int c4 = (lane + 64 * i) * 4;
    f32x4 gv = *(const f32x4*)(norm_g + c4);
    s16x4 ov;
    #pragma unroll
    for (int j = 0; j < 4; j++) ov[j] = f2bf(o[i * 4 + j] * rs * gv[j]);
    *(s16x4*)(ybf + (size_t)row * 1024 + c4) = ov;
  }
}

__global__ void pool2_kernel(const float* __restrict__ outb, float* __restrict__ part)
{
  int b = blockIdx.x, ch = blockIdx.y, d = threadIdx.x;
  const float* p = outb + ((size_t)(b * 512 + ch * 64)) * 512 + d;
  float s = 0.f;
  #pragma unroll 8
  for (int i = 0; i < 64; i++) s += p[(size_t)i * 512];
  part[(b * 8 + ch) * 512 + d] = s;
}

__global__ void poolred_kernel(const float* __restrict__ part, float* __restrict__ pooled)
{
  int b = blockIdx.x, d = threadIdx.x;
  float s = 0.f;
  #pragma unroll
  for (int c = 0; c < 8; c++) s += part[(b * 8 + c) * 512 + d];
  pooled[b * 512 + d] = s * (1.f / 512.f);
}

__global__ void finalproj_kernel(const float* __restrict__ pooled,
                                 const float* __restrict__ Wp,
                                 const float* __restrict__ bp,
                                 float* __restrict__ out)
{
  int b = blockIdx.x, n = threadIdx.x;
  float acc = bp[n];
  for (int k = 0; k < 512; k++) acc += pooled[b * 512 + k] * Wp[k * 256 + n];
  out[b * 256 + n] = acc;
}

// ---------------------------------------------------------------------------
// Host
// ---------------------------------------------------------------------------
extern "C" void kernel_launch(void* const* d_in, const int* in_sizes, int n_in,
                              void* d_out, int out_size, void* d_ws, size_t ws_size,
                              hipStream_t stream)
{
  const int*   ids      = (const int*)d_in[0];
  const int*   amask    = (const int*)d_in[1];
  const float* tok_emb  = (const float*)d_in[2];
  const float* pos_emb  = (const float*)d_in[3];
  const float* type_emb = (const float*)d_in[4];
  const float* emb_g    = (const float*)d_in[5];
  const float* emb_b    = (const float*)d_in[6];
  const float* Wq = (const float*)d_in[7];   const float* bq = (const float*)d_in[8];
  const float* Wk = (const float*)d_in[9];   const float* bk = (const float*)d_in[10];
  const float* Wv = (const float*)d_in[11];  const float* bv = (const float*)d_in[12];
  const float* Wo = (const float*)d_in[13];  const float* bo = (const float*)d_in[14];
  const float* ln1g = (const float*)d_in[15]; const float* ln1b = (const float*)d_in[16];
  const float* Wf1 = (const float*)d_in[17]; const float* bf1 = (const float*)d_in[18];
  const float* Wf2 = (const float*)d_in[19]; const float* bf2 = (const float*)d_in[20];
  const float* ln2g = (const float*)d_in[21]; const float* ln2b = (const float*)d_in[22];
  const float* W_pb = (const float*)d_in[23]; const float* b_pb = (const float*)d_in[24];
  const float* W_in = (const float*)d_in[25];
  const float* conv_w = (const float*)d_in[26]; const float* conv_b = (const float*)d_in[27];
  const float* dt_bias = (const float*)d_in[28]; const float* A_log = (const float*)d_in[29];
  const float* Dskip = (const float*)d_in[30]; const float* norm_g = (const float*)d_in[31];
  const float* W_out = (const float*)d_in[32];
  const float* W_proj = (const float*)d_in[33]; const float* b_proj = (const float*)d_in[34];

  char* base = (char*)d_ws;
  const size_t o_xb   = 0;
  const size_t o_wall = 25165824;
  const size_t o_bv   = o_wall + 169869312;
  const size_t o_cb   = o_bv + 65536;
  const size_t o_gtb  = o_cb + 131072;
  const size_t o_qkv  = o_gtb + 25165824;
  const size_t o_ao   = o_qkv + 75497472;
  const size_t o_ff   = o_ao + 25165824;
  const size_t bert_end = o_ff + 100663296;        // 421,724,160
  const size_t o_hw  = o_wall;
  const size_t o_xm  = o_hw + 4325376;
  const size_t o_zx  = o_xm + 16777216;
  const size_t o_xc  = o_zx + 76021760;
  const size_t o_dt  = o_xc + 83886080;
  const size_t o_dA  = o_dt + 1048576;
  const size_t o_y   = o_dA + 1048576;
  const size_t o_ybf = o_y  + 67108864;
  const size_t o_ob  = o_ybf + 33554432;
  const size_t o_pl  = o_ob + 33554432;
  const size_t o_pp  = o_pl + 65536;
  const size_t head_end = o_pp + 524288;
  const size_t need = (head_end > bert_end ? head_end : bert_end);
  if (ws_size < need) return;

  short* xb   = (short*)(base + o_xb);
  short* wall = (short*)(base + o_wall);
  float* bvp  = (float*)(base + o_bv);
  float* cbia = (float*)(base + o_cb);
  short* gtb  = (short*)(base + o_gtb);
  short* qkvb = (short*)(base + o_qkv);
  short* aob  = (short*)(base + o_ao);
  short* ffb  = (short*)(base + o_ff);
  short* hw   = (short*)(base + o_hw);
  short* xm   = (short*)(base + o_xm);
  short* zx   = (short*)(base + o_zx);
  float* xc   = (float*)(base + o_xc);
  float* dtb  = (float*)(base + o_dt);
  float* dAb  = (float*)(base + o_dA);
  float* yb   = (float*)(base + o_y);
  short* ybf  = (short*)(base + o_ybf);
  float* ob   = (float*)(base + o_ob);
  float* pl   = (float*)(base + o_pl);
  float* pp   = (float*)(base + o_pp);

  short* w_pbt  = hw;
  short* w_int  = w_pbt + 393216;
  short* w_outt = w_int + 1245184;

  const int M = 16384;
  dim3 blk(256);

  transconv4_all_kernel<<<dim3(24, 24, 48), blk, 0, stream>>>(Wq, Wk, Wv, Wo, wall);
  transconv_f1_all_kernel<<<dim3(96, 24, 12), blk, 0, stream>>>(Wf1, wall);
  transconv_f2_all_kernel<<<dim3(24, 96, 12), blk, 0, stream>>>(Wf2, wall);
  concatbias_all_kernel<<<108, 256, 0, stream>>>(bq, bk, bv, cbia);

  maskbias_kernel<<<64, 256, 0, stream>>>(amask, bvp);
  embed_ln_kernel<<<16384, 256, 0, stream>>>(ids, tok_emb, pos_emb, type_emb,
                                             emb_g, emb_b, xb);

  for (int l = 0; l < 12; l++) {
    short* wl = wall + (size_t)l * 7077888;
    gemm3<1, 2, 128><<<dim3(18, 128), 512, 0, stream>>>(xb, wl, cbia + l * 2304, qkvb, M, 2304, 768);
    attn_kernel<<<dim3(4, 12, 32), 512, 0, stream>>>(qkvb, bvp, aob);
    gemm3<1, 2, 128><<<dim3(6, 128), 512, 0, stream>>>(aob, wl + 3ull * 589824, bo + l * 768, gtb, M, 768, 768);
    add_ln_kernel<<<4096, 256, 0, stream>>>(xb, gtb, ln1g + l * 768, ln1b + l * 768);
    gemm3<2, 2, 128><<<dim3(24, 128), 512, 0, stream>>>(xb, wl + 2359296, bf1 + l * 3072, ffb, M, 3072, 768);
    gemm3<1, 2, 128><<<dim3(6, 128), 512, 0, stream>>>(ffb, wl + 4718592, bf2 + l * 768, gtb, M, 768, 3072);
    add_ln_kernel<<<4096, 256, 0, stream>>>(xb, gtb, ln2g + l * 768, ln2b + l * 768);
  }

  // ---- head ----
  transconv_kernel<<<dim3(16, 24), blk, 0, stream>>>(W_pb, w_pbt, 768, 512, 512);
  gemm2<1><<<dim3(4, 128), blk, 0, stream>>>(xb, w_pbt, b_pb, xm, M, 512, 768);
  transconv_kernel<<<dim3(76, 16), blk, 0, stream>>>(W_in, w_int, 512, 2320, 2432);
  gemm2<1><<<dim3(19, 128), blk, 0, stream>>>(xm, w_int, nullptr, zx, M, 2320, 512);
  dtda_kernel<<<1024, 256, 0, stream>>>(zx, dt_bias, A_log, dtb, dAb);
  conv2_kernel<<<10240, 256, 0, stream>>>(zx, conv_w, conv_b, xc);
  scan_kernel<<<512, 256, 0, stream>>>(dtb, dAb, xc, yb);
  ycombine_kernel<<<4096, 256, 0, stream>>>(yb, xc, zx, Dskip, norm_g, ybf);
  transconv_kernel<<<dim3(16, 32), blk, 0, stream>>>(W_out, w_outt, 1024, 512, 512);
  gemm2<0><<<dim3(4, 128), blk, 0, stream>>>(ybf, w_outt, nullptr, ob, M, 512, 1024);
  pool2_kernel<<<dim3(32, 8), 512, 0, stream>>>(ob, pp);
  poolred_kernel<<<32, 512, 0, stream>>>(pp, pl);
  finalproj_kernel<<<32, 256, 0, stream>>>(pl, W_proj, b_proj, (float*)d_out);
}